// Round 18
// baseline (80.133 us; speedup 1.0000x reference)
//
#include <hip/hip_runtime.h>
#include <math.h>

typedef _Float16 f16x8 __attribute__((ext_vector_type(8)));
typedef _Float16 f16x2 __attribute__((ext_vector_type(2)));
typedef float    f32x4 __attribute__((ext_vector_type(4)));

union F16x8u { f16x8 v; f16x2 h[4]; };

__device__ __forceinline__ float cos1_hw(float x) { return __builtin_amdgcn_cosf(x); }
__device__ __forceinline__ float sin1_hw(float x) { return __builtin_amdgcn_sinf(x); }

__device__ __forceinline__ f16x2 pkrtz(float a, float b)
{
    return __builtin_bit_cast(f16x2, __builtin_amdgcn_cvt_pkrtz(a, b));
}

// ---------------------------------------------------------------------------
// ROUND 24 = INTRA-WAVE ILP-2 (two independent tiles per iteration).
// r23 verdict: 256+ regs/wave available, time unchanged -> spills NOT the
// wall. Remaining consistent picture: each tile is a serial chain
// (E1-trans -> rot -> 8-deep MFMA -> acc-read -> apply chain), ~2325 cy/tile
// per SIMD with ~700 cy no-issue gaps; inter-wave overlap isn't filling
// them (avg ~11/16 waves resident). Every prior edit changed scheduling
// *hints* or instruction count -- never the wave's own ILP.
// This round: process tiles in PAIRS with fully independent A/B chains
// (trans, E1 frags, MFMA accs, E2, apply all duplicated). The wave's second
// chain fills the first's bubbles regardless of wave scheduling. Register
// cost ~190 < 256 budget (proven free by r23's 512-thr shape).
// Per-tile math byte-identical to r17/r8 -> absmax 0.015625.
// Predicted: kernel 31.5 -> 19-23us, dur 77 -> 64-68. Null -> trans-count
// reduction (12->4 per tile) is the final lever.
// ---------------------------------------------------------------------------

__global__ __launch_bounds__(512, 2)
void fourier_fused(const float* __restrict__ y,
                   const float* __restrict__ xnew,
                   float* __restrict__ out)
{
    __shared__ _Float16 Yt [64 * 72];    // Y^T f16: Yt[n2][n1], pitch 72
    __shared__ _Float16 Trl[64 * 72];    // T re: Trl[k][n2]
    __shared__ _Float16 Til[64 * 72];    // T im
    __shared__ _Float16 FrL[64 * 72];    // F^T re: FrL[m][k]
    __shared__ _Float16 FiL[64 * 72];    // F^T im
    __shared__ float2   XY[1024];        // sample coords (1024 points)
    __shared__ float2   tw[64];          // (cos, sin)(2pi n/64)

    const int tid   = threadIdx.x;       // 0..511
    const int batch = blockIdx.x >> 4;
    const int sgrp  = blockIdx.x & 15;                // 16 blocks per batch
    const int pbase = (batch << 14) + (sgrp << 10);   // 1024 points

    // ---- stage xnew + y (transposed f16) + twiddles ----
    ((float4*)XY)[tid] = ((const float4*)(xnew + ((size_t)pbase << 1)))[tid];
#pragma unroll
    for (int i = 0; i < 2; ++i) {
        const int f = tid + (i << 9);        // float4 index 0..1023
        const float4 v = ((const float4*)(y + (batch << 12)))[f];
        const int n1 = f >> 4;
        const int n2 = (f & 15) << 2;
        Yt[(n2 + 0) * 72 + n1] = (_Float16)v.x;
        Yt[(n2 + 1) * 72 + n1] = (_Float16)v.y;
        Yt[(n2 + 2) * 72 + n1] = (_Float16)v.z;
        Yt[(n2 + 3) * 72 + n1] = (_Float16)v.w;
    }
    if (tid < 64) {
        const float a = (float)tid * (1.0f / 64.0f);
        tw[tid] = make_float2(cos1_hw(a), sin1_hw(a));
    }
    __syncthreads();

    const int lane = tid & 63;
    const int wv   = tid >> 6;           // 0..7
    const int quad = lane >> 4;
    const int lrow = lane & 15;

    // ---- DFT pass A (MFMA): T[k][n2] = sum_n1 W[k][n1] Y[n1][n2] ----
#pragma unroll
    for (int tt = 0; tt < 2; ++tt) {
        const int t    = wv + (tt << 3);
        const int rt   = t >> 2;
        const int ct   = t & 3;
        const int krow = (rt << 4) + lrow;
        f32x4 Tr = (f32x4){0.f, 0.f, 0.f, 0.f};
        f32x4 Ti = (f32x4){0.f, 0.f, 0.f, 0.f};
#pragma unroll
        for (int kt = 0; kt < 2; ++kt) {
            const int n1b = (kt << 5) + (quad << 3);
            F16x8u cf, sn;                  // cos, -sin  (W = c - i s)
#pragma unroll
            for (int jp = 0; jp < 4; ++jp) {
                const float2 wa = tw[(krow * (n1b + 2 * jp    )) & 63];
                const float2 wb = tw[(krow * (n1b + 2 * jp + 1)) & 63];
                cf.h[jp] = pkrtz(wa.x, wb.x);
                sn.h[jp] = pkrtz(-wa.y, -wb.y);
            }
            const f16x8 yf = *(const f16x8*)&Yt[((ct << 4) + lrow) * 72 + n1b];
            Tr = __builtin_amdgcn_mfma_f32_16x16x32_f16(cf.v, yf, Tr, 0, 0, 0);
            Ti = __builtin_amdgcn_mfma_f32_16x16x32_f16(sn.v, yf, Ti, 0, 0, 0);
        }
#pragma unroll
        for (int reg = 0; reg < 4; ++reg) {
            const int k = (rt << 4) + (quad << 2) + reg;
            Trl[k * 72 + (ct << 4) + lrow] = (_Float16)Tr[reg];
            Til[k * 72 + (ct << 4) + lrow] = (_Float16)Ti[reg];
        }
    }
    __syncthreads();

    // ---- DFT pass B (MFMA): F^T[m][k] = sum_n2 W2[m][n2] T^T[n2][k] ----
#pragma unroll
    for (int tt = 0; tt < 2; ++tt) {
        const int t    = wv + (tt << 3);
        const int mt2  = t >> 2;
        const int ct2  = t & 3;
        const int mrow = (mt2 << 4) + lrow;
        f32x4 Fr = (f32x4){0.f, 0.f, 0.f, 0.f};
        f32x4 Fi = (f32x4){0.f, 0.f, 0.f, 0.f};
#pragma unroll
        for (int kt = 0; kt < 2; ++kt) {
            const int n2b = (kt << 5) + (quad << 3);
            F16x8u cf, sf, sn;
#pragma unroll
            for (int jp = 0; jp < 4; ++jp) {
                const float2 wa = tw[(mrow * (n2b + 2 * jp    )) & 63];
                const float2 wb = tw[(mrow * (n2b + 2 * jp + 1)) & 63];
                cf.h[jp] = pkrtz(wa.x, wb.x);
                sf.h[jp] = pkrtz(wa.y, wb.y);
                sn.h[jp] = pkrtz(-wa.y, -wb.y);
            }
            const f16x8 btr = *(const f16x8*)&Trl[((ct2 << 4) + lrow) * 72 + n2b];
            const f16x8 bti = *(const f16x8*)&Til[((ct2 << 4) + lrow) * 72 + n2b];
            Fr = __builtin_amdgcn_mfma_f32_16x16x32_f16(cf.v, btr, Fr, 0, 0, 0);
            Fr = __builtin_amdgcn_mfma_f32_16x16x32_f16(sf.v, bti, Fr, 0, 0, 0);
            Fi = __builtin_amdgcn_mfma_f32_16x16x32_f16(cf.v, bti, Fi, 0, 0, 0);
            Fi = __builtin_amdgcn_mfma_f32_16x16x32_f16(sn.v, btr, Fi, 0, 0, 0);
        }
#pragma unroll
        for (int reg = 0; reg < 4; ++reg) {
            const int m = (mt2 << 4) + (quad << 2) + reg;
            FrL[m * 72 + (ct2 << 4) + lrow] = (_Float16)Fr[reg];
            FiL[m * 72 + (ct2 << 4) + lrow] = (_Float16)Fi[reg];
        }
    }
    __syncthreads();

    // ---- hoist A-operand (F^T) fragments once per wave ----
    f16x8 Ar[4][2], Ai[4][2];
#pragma unroll
    for (int nt = 0; nt < 4; ++nt)
#pragma unroll
        for (int kt = 0; kt < 2; ++kt) {
            const int off = ((nt << 4) + lrow) * 72 + (kt << 5) + (quad << 3);
            Ar[nt][kt] = *(const f16x8*)&FrL[off];
            Ai[nt][kt] = *(const f16x8*)&FiL[off];
        }

    // ---- interp: 4 PAIRS of tiles; A/B chains fully independent ----
#pragma unroll 1
    for (int mtp = 0; mtp < 4; ++mtp) {
        const int lptA = (wv << 7) + (mtp << 5);
        const int lptB = lptA + 16;
        const float2 xvA = XY[lptA + lrow];
        const float2 xvB = XY[lptB + lrow];

        // ---- E1 heads (A and B interleaved, independent) ----
        const float cs1A = cos1_hw(xvA.x);
        const float cs1B = cos1_hw(xvB.x);
        const float sn1A = sin1_hw(xvA.x);
        const float sn1B = sin1_hw(xvB.x);
        const float cs1bA = fmaf(cs1A, cs1A, -(sn1A * sn1A));
        const float cs1bB = fmaf(cs1B, cs1B, -(sn1B * sn1B));
        const float sn1bA = 2.0f * cs1A * sn1A;
        const float sn1bB = 2.0f * cs1B * sn1B;

        F16x8u ur0A, ui0A, un0A, ur1A, ui1A, un1A;
        F16x8u ur0B, ui0B, un0B, ur1B, ui1B, un1B;
#pragma unroll
        for (int kt = 0; kt < 2; ++kt) {
            const float fb = (float)((quad << 3) - (kt ? 32 : 0));
            float thA = xvA.x * fb;  thA -= floorf(thA);
            float thB = xvB.x * fb;  thB -= floorf(thB);
            float er0A = cos1_hw(thA), ei0A = sin1_hw(thA);
            float er0B = cos1_hw(thB), ei0B = sin1_hw(thB);
            float er1A = fmaf(-ei0A, sn1A, er0A * cs1A);
            float ei1A = fmaf( er0A, sn1A, ei0A * cs1A);
            float er1B = fmaf(-ei0B, sn1B, er0B * cs1B);
            float ei1B = fmaf( er0B, sn1B, ei0B * cs1B);

            F16x8u& urA = kt ? ur1A : ur0A;
            F16x8u& uiA = kt ? ui1A : ui0A;
            F16x8u& unA = kt ? un1A : un0A;
            F16x8u& urB = kt ? ur1B : ur0B;
            F16x8u& uiB = kt ? ui1B : ui0B;
            F16x8u& unB = kt ? un1B : un0B;
#pragma unroll
            for (int jp = 0; jp < 4; ++jp) {
                urA.h[jp] = pkrtz(er0A, er1A);
                urB.h[jp] = pkrtz(er0B, er1B);
                uiA.h[jp] = pkrtz(ei0A, ei1A);
                uiB.h[jp] = pkrtz(ei0B, ei1B);
                unA.h[jp] = pkrtz(-ei0A, -ei1A);
                unB.h[jp] = pkrtz(-ei0B, -ei1B);
                if (jp < 3) {
                    const float e0A = fmaf(-ei0A, sn1bA, er0A * cs1bA);
                    ei0A = fmaf(er0A, sn1bA, ei0A * cs1bA);
                    er0A = e0A;
                    const float e0B = fmaf(-ei0B, sn1bB, er0B * cs1bB);
                    ei0B = fmaf(er0B, sn1bB, ei0B * cs1bB);
                    er0B = e0B;
                    const float e1A = fmaf(-ei1A, sn1bA, er1A * cs1bA);
                    ei1A = fmaf(er1A, sn1bA, ei1A * cs1bA);
                    er1A = e1A;
                    const float e1B = fmaf(-ei1B, sn1bB, er1B * cs1bB);
                    ei1B = fmaf(er1B, sn1bB, ei1B * cs1bB);
                    er1B = e1B;
                }
            }
        }

        // ---- E2 seeds (A and B) ----
        const float cs2A = cos1_hw(xvA.y), cs2B = cos1_hw(xvB.y);
        const float sn2A = sin1_hw(xvA.y), sn2B = sin1_hw(xvB.y);
        float t16A = xvA.y * 16.0f;  t16A -= floorf(t16A);
        float t16B = xvB.y * 16.0f;  t16B -= floorf(t16B);
        const float c16A = cos1_hw(t16A), c16B = cos1_hw(t16B);
        const float s16A = sin1_hw(t16A), s16B = sin1_hw(t16B);
        const float cm32A = fmaf(c16A, c16A, -(s16A * s16A));
        const float cm32B = fmaf(c16B, c16B, -(s16B * s16B));
        const float sm32A = -2.0f * c16A * s16A;
        const float sm32B = -2.0f * c16B * s16B;

        float thAA = xvA.y * (float)(quad << 2);  thAA -= floorf(thAA);
        float thAB = xvB.y * (float)(quad << 2);  thAB -= floorf(thAB);
        const float erAA = cos1_hw(thAA), erAB = cos1_hw(thAB);
        const float eiAA = sin1_hw(thAA), eiAB = sin1_hw(thAB);

        float brA[4], biA[4], brB[4], biB[4];
        brA[0] = erAA;                               biA[0] = eiAA;
        brB[0] = erAB;                               biB[0] = eiAB;
        brA[1] = fmaf(-eiAA, s16A, erAA * c16A);     biA[1] = fmaf(erAA, s16A, eiAA * c16A);
        brB[1] = fmaf(-eiAB, s16B, erAB * c16B);     biB[1] = fmaf(erAB, s16B, eiAB * c16B);
        brA[2] = fmaf(-eiAA, sm32A, erAA * cm32A);   biA[2] = fmaf(erAA, sm32A, eiAA * cm32A);
        brB[2] = fmaf(-eiAB, sm32B, erAB * cm32B);   biB[2] = fmaf(erAB, sm32B, eiAB * cm32B);
        brA[3] = fmaf(-biA[2], s16A, brA[2] * c16A); biA[3] = fmaf(brA[2], s16A, biA[2] * c16A);
        brB[3] = fmaf(-biB[2], s16B, brB[2] * c16B); biB[3] = fmaf(brB[2], s16B, biB[2] * c16B);

        // ---- per nt: MFMA A, MFMA B (independent accs), apply A, apply B ----
        float redA = 0.0f, redB = 0.0f;
#pragma unroll
        for (int nt = 0; nt < 4; ++nt) {
            f32x4 GrA = (f32x4){0.f, 0.f, 0.f, 0.f};
            f32x4 GiA = (f32x4){0.f, 0.f, 0.f, 0.f};
            f32x4 GrB = (f32x4){0.f, 0.f, 0.f, 0.f};
            f32x4 GiB = (f32x4){0.f, 0.f, 0.f, 0.f};
            GrA = __builtin_amdgcn_mfma_f32_16x16x32_f16(Ar[nt][0], ur0A.v, GrA, 0, 0, 0);
            GrB = __builtin_amdgcn_mfma_f32_16x16x32_f16(Ar[nt][0], ur0B.v, GrB, 0, 0, 0);
            GrA = __builtin_amdgcn_mfma_f32_16x16x32_f16(Ai[nt][0], un0A.v, GrA, 0, 0, 0);
            GrB = __builtin_amdgcn_mfma_f32_16x16x32_f16(Ai[nt][0], un0B.v, GrB, 0, 0, 0);
            GrA = __builtin_amdgcn_mfma_f32_16x16x32_f16(Ar[nt][1], ur1A.v, GrA, 0, 0, 0);
            GrB = __builtin_amdgcn_mfma_f32_16x16x32_f16(Ar[nt][1], ur1B.v, GrB, 0, 0, 0);
            GrA = __builtin_amdgcn_mfma_f32_16x16x32_f16(Ai[nt][1], un1A.v, GrA, 0, 0, 0);
            GrB = __builtin_amdgcn_mfma_f32_16x16x32_f16(Ai[nt][1], un1B.v, GrB, 0, 0, 0);
            GiA = __builtin_amdgcn_mfma_f32_16x16x32_f16(Ar[nt][0], ui0A.v, GiA, 0, 0, 0);
            GiB = __builtin_amdgcn_mfma_f32_16x16x32_f16(Ar[nt][0], ui0B.v, GiB, 0, 0, 0);
            GiA = __builtin_amdgcn_mfma_f32_16x16x32_f16(Ai[nt][0], ur0A.v, GiA, 0, 0, 0);
            GiB = __builtin_amdgcn_mfma_f32_16x16x32_f16(Ai[nt][0], ur0B.v, GiB, 0, 0, 0);
            GiA = __builtin_amdgcn_mfma_f32_16x16x32_f16(Ar[nt][1], ui1A.v, GiA, 0, 0, 0);
            GiB = __builtin_amdgcn_mfma_f32_16x16x32_f16(Ar[nt][1], ui1B.v, GiB, 0, 0, 0);
            GiA = __builtin_amdgcn_mfma_f32_16x16x32_f16(Ai[nt][1], ur1A.v, GiA, 0, 0, 0);
            GiB = __builtin_amdgcn_mfma_f32_16x16x32_f16(Ai[nt][1], ur1B.v, GiB, 0, 0, 0);

            float erA = brA[nt], eiA = biA[nt], accA = 0.0f;
            float erB = brB[nt], eiB = biB[nt], accB = 0.0f;
#pragma unroll
            for (int reg = 0; reg < 4; ++reg) {
                accA = fmaf(GrA[reg],  erA, accA);
                accB = fmaf(GrB[reg],  erB, accB);
                accA = fmaf(GiA[reg], -eiA, accA);
                accB = fmaf(GiB[reg], -eiB, accB);
                if (reg < 3) {
                    const float t2A = fmaf(-eiA, sn2A, erA * cs2A);
                    eiA = fmaf(erA, sn2A, eiA * cs2A);
                    erA = t2A;
                    const float t2B = fmaf(-eiB, sn2B, erB * cs2B);
                    eiB = fmaf(erB, sn2B, eiB * cs2B);
                    erB = t2B;
                }
            }
            redA += accA;
            redB += accB;
        }

        redA += __shfl_xor(redA, 16, 64);
        redB += __shfl_xor(redB, 16, 64);
        redA += __shfl_xor(redA, 32, 64);
        redB += __shfl_xor(redB, 32, 64);
        if (lane < 16) {
            out[pbase + lptA + lane] = redA * (1.0f / 4096.0f);
            out[pbase + lptB + lane] = redB * (1.0f / 4096.0f);
        }
    }
}

extern "C" void kernel_launch(void* const* d_in, const int* in_sizes, int n_in,
                              void* d_out, int out_size, void* d_ws, size_t ws_size,
                              hipStream_t stream)
{
    const float* y    = (const float*)d_in[0];   // [32, 64, 64]
    const float* xnew = (const float*)d_in[1];   // [32, 128, 128, 2]
    float* out        = (float*)d_out;           // [32, 128, 128]

    // ONE dispatch: 32 batches x 16 segment-groups = 512 blocks (512 thr).
    fourier_fused<<<512, 512, 0, stream>>>(y, xnew, out);
}